// Round 1
// baseline (259.171 us; speedup 1.0000x reference)
//
#include <hip/hip_runtime.h>
#include <math.h>

#define NN 32768
#define EN 1048576
#define CAP 128

// C = 1/sqrt(E[gelu(z)^2]) , E = 1/3 + 1/(2*pi*sqrt(3))
#define C_GELU_F 1.5335262f

// ---------------- bucket scatter: edges -> per-receiver slots ----------------
__global__ __launch_bounds__(256) void scatter_k(const int* __restrict__ snd,
                                                 const int* __restrict__ rcv,
                                                 int* __restrict__ cur,
                                                 int* __restrict__ bkt) {
    int e = blockIdx.x * 256 + threadIdx.x;
    int r = rcv[e];
    int s = snd[e];
    int p = atomicAdd(&cur[r], 1);
    if (p < CAP) bkt[(r << 7) + p] = s;
}

// ---------------- aggregation: 16 lanes per node, lane u owns agg[n,u,:] ----
__global__ __launch_bounds__(256) void agg_k(const float* __restrict__ x,
                                             const float* __restrict__ pos,
                                             const int* __restrict__ cur,
                                             const int* __restrict__ bkt,
                                             float* __restrict__ agg) {
    int n = blockIdx.x * 16 + (threadIdx.x >> 4);
    int u = threadIdx.x & 15;
    int cnt = cur[n]; cnt = cnt > CAP ? CAP : cnt;
    float rx = pos[3*n], ry = pos[3*n+1], rz = pos[3*n+2];
    float acc[16];
#pragma unroll
    for (int j = 0; j < 16; ++j) acc[j] = 0.f;
    const int base = n << 7;

    const float s3   = 1.7320508075688772f;   // sqrt(3)
    const float s5   = 2.2360679774997896f;   // sqrt(5)
    const float s15  = 3.8729833462074170f;   // sqrt(15)
    const float s7   = 2.6457513110645907f;   // sqrt(7)
    const float s105 = 10.246950765959598f;   // sqrt(105)
    const float s35_8 = 2.0916500663351889f;  // sqrt(35/8)
    const float s21_8 = 1.6201851746019651f;  // sqrt(21/8)

    for (int k = 0; k < cnt; ++k) {
        int s = bkt[base + k];
        float vx = rx - pos[3*s], vy = ry - pos[3*s+1], vz = rz - pos[3*s+2];
        float sv = x[(s << 4) + u];
        float n2 = vx*vx + vy*vy + vz*vz;
        float inv;
        if (n2 > 0.f) {
            inv = rsqrtf(n2);
            inv = inv * (1.5f - 0.5f * n2 * inv * inv);   // Newton: ~exact f32
        } else inv = 0.f;
        float X = vx*inv, Y = vy*inv, Z = vz*inv;
        float XX = X*X, YY = Y*Y, ZZ = Z*Z;

        acc[0]  += sv;                                  // l=0
        acc[1]  += sv * (s3*X);                         // Y1
        acc[2]  += sv * (s3*Y);
        acc[3]  += sv * (s3*Z);
        acc[4]  += sv * (s15*X*Y);                      // Y2
        acc[5]  += sv * (s15*Y*Z);
        acc[6]  += sv * (0.5f*s5*(3.f*ZZ - 1.f));
        acc[7]  += sv * (s15*X*Z);
        acc[8]  += sv * (0.5f*s15*(XX - YY));
        acc[9]  += sv * (s35_8*Y*(3.f*XX - YY));        // Y3
        acc[10] += sv * (s105*X*Y*Z);
        acc[11] += sv * (s21_8*Y*(5.f*ZZ - 1.f));
        acc[12] += sv * (0.5f*s7*Z*(5.f*ZZ - 3.f));
        acc[13] += sv * (s21_8*X*(5.f*ZZ - 1.f));
        acc[14] += sv * (0.5f*s105*Z*(XX - YY));
        acc[15] += sv * (s35_8*X*(XX - 3.f*YY));
    }

    float4* o = (float4*)(agg + (n << 8) + (u << 4));
    o[0] = make_float4(acc[0],  acc[1],  acc[2],  acc[3]);
    o[1] = make_float4(acc[4],  acc[5],  acc[6],  acc[7]);
    o[2] = make_float4(acc[8],  acc[9],  acc[10], acc[11]);
    o[3] = make_float4(acc[12], acc[13], acc[14], acc[15]);
}

// ---------------- node update: thread per (node, j-column) -------------------
// sPre rows stride 516, sPost stride 1028: l-stride mod 32 = 4 -> no 4-way
// LDS bank conflict across the 4 l-groups within a wave.
__global__ __launch_bounds__(256) void upd_k(const float* __restrict__ x,
                                             const float* __restrict__ Wpre,
                                             const float* __restrict__ Wpost,
                                             const float* __restrict__ Wsc,
                                             const float* __restrict__ agg,
                                             float* __restrict__ out) {
    __shared__ float sPre[4*516];
    __shared__ float sPost[4*1028];
    __shared__ float sSc[512];
    int t = threadIdx.x;
    for (int idx = t; idx < 2048; idx += 256)
        sPre[(idx >> 9)*516 + (idx & 511)] = Wpre[idx];
    for (int idx = t; idx < 4096; idx += 256)
        sPost[(idx >> 10)*1028 + (idx & 1023)] = Wpost[idx];
    sSc[t] = Wsc[t];
    sSc[t + 256] = Wsc[t + 256];
    __syncthreads();

    int n = (blockIdx.x * 256 + t) >> 4;
    int j = t & 15;
    int l, i, offl, deg;
    if (j == 0)      { l = 0; i = 0;     offl = 0;   deg = 1; }
    else if (j < 4)  { l = 1; i = j - 1; offl = 32;  deg = 3; }
    else if (j < 9)  { l = 2; i = j - 4; offl = 128; deg = 5; }
    else             { l = 3; i = j - 9; offl = 288; deg = 7; }

    const float c1 = 0.0078125f;            // (1/32 DENOM) * (1/4 inv_in)
    const float c2 = 0.17677669529663687f;  // 1/sqrt(32)

    // p[v] = c1 * sum_u agg[n,u,j] * Wpre[l][u,v]
    const float* ap = agg + (n << 8) + j;
    float p[32];
#pragma unroll
    for (int v = 0; v < 32; ++v) p[v] = 0.f;
    const float* wp = sPre + l * 516;
#pragma unroll
    for (int u = 0; u < 16; ++u) {
        float a = ap[u << 4];
        const float4* w4 = (const float4*)(wp + (u << 5));
#pragma unroll
        for (int vq = 0; vq < 8; ++vq) {
            float4 w = w4[vq];
            p[4*vq+0] += a * w.x;
            p[4*vq+1] += a * w.y;
            p[4*vq+2] += a * w.z;
            p[4*vq+3] += a * w.w;
        }
    }
#pragma unroll
    for (int v = 0; v < 32; ++v) p[v] *= c1;

    if (j == 0) {   // gelu (exact erf) + e3nn second-moment normalization
#pragma unroll
        for (int v = 0; v < 32; ++v) {
            float pv = p[v];
            p[v] = C_GELU_F * 0.5f * pv * (1.f + erff(pv * 0.7071067811865476f));
        }
    }

    // q[w] = c2 * sum_v p[v] * Wpost[l][v,w]
    float q[32];
#pragma unroll
    for (int w = 0; w < 32; ++w) q[w] = 0.f;
    const float* wq = sPost + l * 1028;
#pragma unroll
    for (int v = 0; v < 32; ++v) {
        float pv = p[v];
        const float4* w4 = (const float4*)(wq + (v << 5));
#pragma unroll
        for (int wd = 0; wd < 8; ++wd) {
            float4 w = w4[wd];
            q[4*wd+0] += pv * w.x;
            q[4*wd+1] += pv * w.y;
            q[4*wd+2] += pv * w.z;
            q[4*wd+3] += pv * w.w;
        }
    }
#pragma unroll
    for (int w = 0; w < 32; ++w) q[w] *= c2;

    if (j == 0) {   // shortcut: (x @ Wsc) * 1/4, only the 0e path
        const float* xp = x + (n << 4);
#pragma unroll
        for (int u = 0; u < 16; ++u) {
            float xv = 0.25f * xp[u];
            const float4* w4 = (const float4*)(sSc + (u << 5));
#pragma unroll
            for (int wd = 0; wd < 8; ++wd) {
                float4 w = w4[wd];
                q[4*wd+0] += xv * w.x;
                q[4*wd+1] += xv * w.y;
                q[4*wd+2] += xv * w.z;
                q[4*wd+3] += xv * w.w;
            }
        }
    }

    float* op = out + (n << 9) + offl + i;
#pragma unroll
    for (int w = 0; w < 32; ++w) op[w * deg] = q[w];
}

extern "C" void kernel_launch(void* const* d_in, const int* in_sizes, int n_in,
                              void* d_out, int out_size, void* d_ws, size_t ws_size,
                              hipStream_t stream) {
    const float* x     = (const float*)d_in[0];
    const float* pos   = (const float*)d_in[1];
    const float* Wpre  = (const float*)d_in[2];
    const float* Wpost = (const float*)d_in[3];
    const float* Wsc   = (const float*)d_in[4];
    const int*   snd   = (const int*)d_in[5];
    const int*   rcv   = (const int*)d_in[6];
    float* out = (float*)d_out;

    char* ws = (char*)d_ws;
    int*   cur = (int*)ws;                               // 128 KiB
    int*   bkt = (int*)(ws + (1 << 17));                 // 16 MiB
    float* agg = (float*)(ws + (1 << 17) + (NN*CAP*4));  // 32 MiB

    hipMemsetAsync(cur, 0, NN * sizeof(int), stream);
    scatter_k<<<EN/256, 256, 0, stream>>>(snd, rcv, cur, bkt);
    agg_k<<<NN/16, 256, 0, stream>>>(x, pos, cur, bkt, agg);
    upd_k<<<(NN*16)/256, 256, 0, stream>>>(x, Wpre, Wpost, Wsc, agg, out);
}

// Round 2
// 219.197 us; speedup vs baseline: 1.1824x; 1.1824x over previous
//
#include <hip/hip_runtime.h>
#include <math.h>

#define NN 32768
#define EN 1048576
#define NBIN 256          // coarse bins: bin = rcv >> 7 (128 receivers per bin)
#define BINCAP 8192       // slots per coarse bin (avg 4096, +many sigma)
#define TILE 4096         // edges per bin_k block

// C = 1/sqrt(E[gelu(z)^2]) , E = 1/3 + 1/(2*pi*sqrt(3))
#define C_GELU_F 1.5335262f

// ---------------- pass A: coarse-bin edges, coalesced writes ----------------
// word = (rcv << 15) | snd  (30 bits); bin = word >> 22.
__global__ __launch_bounds__(256) void bin_k(const int* __restrict__ snd,
                                             const int* __restrict__ rcv,
                                             int* __restrict__ bin_cur,
                                             unsigned* __restrict__ binbuf) {
    __shared__ unsigned cnt[NBIN];
    __shared__ unsigned excl[NBIN];
    __shared__ unsigned cur2[NBIN];
    __shared__ unsigned gbase[NBIN];
    __shared__ unsigned stage[TILE];
    int t = threadIdx.x;
    int tile = blockIdx.x * TILE;
    cnt[t] = 0; cur2[t] = 0;
    __syncthreads();

    unsigned w[TILE / 256];
#pragma unroll
    for (int i = 0; i < TILE / 256; ++i) {
        int e = tile + i * 256 + t;
        unsigned r = (unsigned)rcv[e], s = (unsigned)snd[e];
        w[i] = (r << 15) | s;
        atomicAdd(&cnt[w[i] >> 22], 1u);
    }
    __syncthreads();

    // inclusive Kogge-Stone over 256 counters -> excl (exclusive)
    unsigned my = cnt[t];
    excl[t] = my;
    __syncthreads();
    for (int d = 1; d < NBIN; d <<= 1) {
        unsigned v = (t >= d) ? excl[t - d] : 0u;
        __syncthreads();
        excl[t] += v;
        __syncthreads();
    }
    unsigned myexcl = excl[t] - my;
    // reserve global space for this block's bin segments
    gbase[t] = atomicAdd((unsigned*)&bin_cur[t], my);
    __syncthreads();
    excl[t] = myexcl;           // store exclusive scan
    __syncthreads();

    // place into LDS staging grouped by bin
#pragma unroll
    for (int i = 0; i < TILE / 256; ++i) {
        unsigned b = w[i] >> 22;
        unsigned p = excl[b] + atomicAdd(&cur2[b], 1u);
        stage[p] = w[i];
    }
    __syncthreads();

    // coalesced flush: consecutive staged entries of a bin -> consecutive global
    for (int p = t; p < TILE; p += 256) {
        unsigned ww = stage[p];
        unsigned b = ww >> 22;
        unsigned idx = gbase[b] + ((unsigned)p - excl[b]);
        if (idx < BINCAP) binbuf[b * BINCAP + idx] = ww;
    }
}

// ---------------- scan over bins -> global CSR base per bin -----------------
__global__ __launch_bounds__(256) void scan_k(const int* __restrict__ bin_cur,
                                              int* __restrict__ bin_start) {
    __shared__ unsigned sc[NBIN];
    int t = threadIdx.x;
    unsigned my = (unsigned)bin_cur[t];
    sc[t] = my;
    __syncthreads();
    for (int d = 1; d < NBIN; d <<= 1) {
        unsigned v = (t >= d) ? sc[t - d] : 0u;
        __syncthreads();
        sc[t] += v;
        __syncthreads();
    }
    bin_start[t] = (int)(sc[t] - my);
}

// ---------------- pass B: per-bin counting sort -> CSR ----------------------
__global__ __launch_bounds__(256) void csr_k(const int* __restrict__ bin_cur,
                                             const int* __restrict__ bin_start,
                                             const unsigned* __restrict__ binbuf,
                                             int* __restrict__ row_ptr,
                                             int* __restrict__ edge_csr) {
    __shared__ unsigned cnt[128];
    __shared__ unsigned excl[128];
    __shared__ unsigned cur2[128];
    int b = blockIdx.x;
    int t = threadIdx.x;
    int M = bin_cur[b]; M = M > BINCAP ? BINCAP : M;
    int base = bin_start[b];
    if (t < 128) { cnt[t] = 0; cur2[t] = 0; }
    __syncthreads();

    const unsigned* bb = binbuf + b * BINCAP;
    for (int i = t; i < M; i += 256)
        atomicAdd(&cnt[(bb[i] >> 15) & 127], 1u);
    __syncthreads();

    if (t < 128) excl[t] = cnt[t];
    __syncthreads();
    for (int d = 1; d < 128; d <<= 1) {
        unsigned v = (t >= d && t < 128) ? excl[t - d] : 0u;
        __syncthreads();
        if (t < 128) excl[t] += v;
        __syncthreads();
    }
    if (t < 128) {
        unsigned e = excl[t] - cnt[t];
        excl[t] = e;
        row_ptr[(b << 7) + t] = base + (int)e;
        if (b == NBIN - 1 && t == 127) row_ptr[NN] = base + (int)(e + cnt[127]);
    }
    __syncthreads();

    for (int i = t; i < M; i += 256) {
        unsigned ww = bb[i];
        unsigned r7 = (ww >> 15) & 127;
        unsigned dst = excl[r7] + atomicAdd(&cur2[r7], 1u);
        edge_csr[base + dst] = (int)(ww & 0x7FFF);   // 16KB window: L2-dense
    }
}

// ---------------- pack positions into float4 for 16B loads ------------------
__global__ __launch_bounds__(256) void pos_k(const float* __restrict__ pos,
                                             float4* __restrict__ posw) {
    int n = blockIdx.x * 256 + threadIdx.x;
    posw[n] = make_float4(pos[3*n], pos[3*n+1], pos[3*n+2], 0.f);
}

// ---------------- aggregation: 16 lanes per node, lane u owns agg[n,u,:] ----
__global__ __launch_bounds__(256) void agg_k(const float* __restrict__ x,
                                             const float4* __restrict__ posw,
                                             const int* __restrict__ row_ptr,
                                             const int* __restrict__ edge_csr,
                                             float* __restrict__ agg) {
    int n = blockIdx.x * 16 + (threadIdx.x >> 4);
    int u = threadIdx.x & 15;
    int beg = row_ptr[n], end = row_ptr[n + 1];
    float4 rp = posw[n];
    float acc[16];
#pragma unroll
    for (int j = 0; j < 16; ++j) acc[j] = 0.f;

    const float s3   = 1.7320508075688772f;
    const float s5   = 2.2360679774997896f;
    const float s15  = 3.8729833462074170f;
    const float s7   = 2.6457513110645907f;
    const float s105 = 10.246950765959598f;
    const float s35_8 = 2.0916500663351889f;
    const float s21_8 = 1.6201851746019651f;

    for (int k = beg; k < end; ++k) {
        int s = edge_csr[k];
        float4 sp = posw[s];
        float vx = rp.x - sp.x, vy = rp.y - sp.y, vz = rp.z - sp.z;
        float sv = x[(s << 4) + u];
        float n2 = vx*vx + vy*vy + vz*vz;
        float inv;
        if (n2 > 0.f) {
            inv = rsqrtf(n2);
            inv = inv * (1.5f - 0.5f * n2 * inv * inv);   // Newton: ~exact f32
        } else inv = 0.f;
        float X = vx*inv, Y = vy*inv, Z = vz*inv;
        float XX = X*X, YY = Y*Y, ZZ = Z*Z;

        acc[0]  += sv;
        acc[1]  += sv * (s3*X);
        acc[2]  += sv * (s3*Y);
        acc[3]  += sv * (s3*Z);
        acc[4]  += sv * (s15*X*Y);
        acc[5]  += sv * (s15*Y*Z);
        acc[6]  += sv * (0.5f*s5*(3.f*ZZ - 1.f));
        acc[7]  += sv * (s15*X*Z);
        acc[8]  += sv * (0.5f*s15*(XX - YY));
        acc[9]  += sv * (s35_8*Y*(3.f*XX - YY));
        acc[10] += sv * (s105*X*Y*Z);
        acc[11] += sv * (s21_8*Y*(5.f*ZZ - 1.f));
        acc[12] += sv * (0.5f*s7*Z*(5.f*ZZ - 3.f));
        acc[13] += sv * (s21_8*X*(5.f*ZZ - 1.f));
        acc[14] += sv * (0.5f*s105*Z*(XX - YY));
        acc[15] += sv * (s35_8*X*(XX - 3.f*YY));
    }

    float4* o = (float4*)(agg + (n << 8) + (u << 4));
    o[0] = make_float4(acc[0],  acc[1],  acc[2],  acc[3]);
    o[1] = make_float4(acc[4],  acc[5],  acc[6],  acc[7]);
    o[2] = make_float4(acc[8],  acc[9],  acc[10], acc[11]);
    o[3] = make_float4(acc[12], acc[13], acc[14], acc[15]);
}

// ---------------- node update: thread per (node, j-column) -------------------
__global__ __launch_bounds__(256) void upd_k(const float* __restrict__ x,
                                             const float* __restrict__ Wpre,
                                             const float* __restrict__ Wpost,
                                             const float* __restrict__ Wsc,
                                             const float* __restrict__ agg,
                                             float* __restrict__ out) {
    __shared__ float sPre[4*516];
    __shared__ float sPost[4*1028];
    __shared__ float sSc[512];
    int t = threadIdx.x;
    for (int idx = t; idx < 2048; idx += 256)
        sPre[(idx >> 9)*516 + (idx & 511)] = Wpre[idx];
    for (int idx = t; idx < 4096; idx += 256)
        sPost[(idx >> 10)*1028 + (idx & 1023)] = Wpost[idx];
    sSc[t] = Wsc[t];
    sSc[t + 256] = Wsc[t + 256];
    __syncthreads();

    int n = (blockIdx.x * 256 + t) >> 4;
    int j = t & 15;
    int l, i, offl, deg;
    if (j == 0)      { l = 0; i = 0;     offl = 0;   deg = 1; }
    else if (j < 4)  { l = 1; i = j - 1; offl = 32;  deg = 3; }
    else if (j < 9)  { l = 2; i = j - 4; offl = 128; deg = 5; }
    else             { l = 3; i = j - 9; offl = 288; deg = 7; }

    const float c1 = 0.0078125f;            // (1/32 DENOM) * (1/4 inv_in)
    const float c2 = 0.17677669529663687f;  // 1/sqrt(32)

    const float* ap = agg + (n << 8) + j;
    float p[32];
#pragma unroll
    for (int v = 0; v < 32; ++v) p[v] = 0.f;
    const float* wp = sPre + l * 516;
#pragma unroll
    for (int u = 0; u < 16; ++u) {
        float a = ap[u << 4];
        const float4* w4 = (const float4*)(wp + (u << 5));
#pragma unroll
        for (int vq = 0; vq < 8; ++vq) {
            float4 w = w4[vq];
            p[4*vq+0] += a * w.x;
            p[4*vq+1] += a * w.y;
            p[4*vq+2] += a * w.z;
            p[4*vq+3] += a * w.w;
        }
    }
#pragma unroll
    for (int v = 0; v < 32; ++v) p[v] *= c1;

    if (j == 0) {
#pragma unroll
        for (int v = 0; v < 32; ++v) {
            float pv = p[v];
            p[v] = C_GELU_F * 0.5f * pv * (1.f + erff(pv * 0.7071067811865476f));
        }
    }

    float q[32];
#pragma unroll
    for (int w = 0; w < 32; ++w) q[w] = 0.f;
    const float* wq = sPost + l * 1028;
#pragma unroll
    for (int v = 0; v < 32; ++v) {
        float pv = p[v];
        const float4* w4 = (const float4*)(wq + (v << 5));
#pragma unroll
        for (int wd = 0; wd < 8; ++wd) {
            float4 w = w4[wd];
            q[4*wd+0] += pv * w.x;
            q[4*wd+1] += pv * w.y;
            q[4*wd+2] += pv * w.z;
            q[4*wd+3] += pv * w.w;
        }
    }
#pragma unroll
    for (int w = 0; w < 32; ++w) q[w] *= c2;

    if (j == 0) {
        const float* xp = x + (n << 4);
#pragma unroll
        for (int u = 0; u < 16; ++u) {
            float xv = 0.25f * xp[u];
            const float4* w4 = (const float4*)(sSc + (u << 5));
#pragma unroll
            for (int wd = 0; wd < 8; ++wd) {
                float4 w = w4[wd];
                q[4*wd+0] += xv * w.x;
                q[4*wd+1] += xv * w.y;
                q[4*wd+2] += xv * w.z;
                q[4*wd+3] += xv * w.w;
            }
        }
    }

    float* op = out + (n << 9) + offl + i;
#pragma unroll
    for (int w = 0; w < 32; ++w) op[w * deg] = q[w];
}

extern "C" void kernel_launch(void* const* d_in, const int* in_sizes, int n_in,
                              void* d_out, int out_size, void* d_ws, size_t ws_size,
                              hipStream_t stream) {
    const float* x     = (const float*)d_in[0];
    const float* pos   = (const float*)d_in[1];
    const float* Wpre  = (const float*)d_in[2];
    const float* Wpost = (const float*)d_in[3];
    const float* Wsc   = (const float*)d_in[4];
    const int*   snd   = (const int*)d_in[5];
    const int*   rcv   = (const int*)d_in[6];
    float* out = (float*)d_out;

    char* ws = (char*)d_ws;
    int*      bin_cur   = (int*)(ws);                    // 1 KiB
    int*      bin_start = (int*)(ws + 1024);             // 1 KiB
    int*      row_ptr   = (int*)(ws + 2048);             // 128 KiB + 4
    float4*   posw      = (float4*)(ws + 0x30000);       // 512 KiB
    int*      edge_csr  = (int*)(ws + 0xB0000);          // 4 MiB
    unsigned* binbuf    = (unsigned*)(ws + 0x500000);    // 8 MiB
    float*    agg       = (float*)(ws + 0x1000000);      // 32 MiB

    hipMemsetAsync(bin_cur, 0, NBIN * sizeof(int), stream);
    bin_k<<<EN / TILE, 256, 0, stream>>>(snd, rcv, bin_cur, binbuf);
    scan_k<<<1, 256, 0, stream>>>(bin_cur, bin_start);
    csr_k<<<NBIN, 256, 0, stream>>>(bin_cur, bin_start, binbuf, row_ptr, edge_csr);
    pos_k<<<NN / 256, 256, 0, stream>>>(pos, posw);
    agg_k<<<NN / 16, 256, 0, stream>>>(x, posw, row_ptr, edge_csr, agg);
    upd_k<<<(NN * 16) / 256, 256, 0, stream>>>(x, Wpre, Wpost, Wsc, agg, out);
}